// Round 2
// baseline (1864.064 us; speedup 1.0000x reference)
//
#include <hip/hip_runtime.h>
#include <stdint.h>

#define N_NODES 100000
#define N_EDGES 1600000
#define HDIM    128
#define KSTEPS  10

// ---- CSR-build scan config ----
#define SCAN_T     256
#define SCAN_I     4
#define SCAN_ELEMS (SCAN_T * SCAN_I)                         // 1024
#define SCAN_NB    ((N_NODES + SCAN_ELEMS - 1) / SCAN_ELEMS) // 98

// ---------------- degree count over dst (excluding self loop) ----------------
__global__ void k_count(const int* __restrict__ eidx, int* __restrict__ cnt) {
    int e = blockIdx.x * blockDim.x + threadIdx.x;
    if (e < N_EDGES) {
        unsigned d = (unsigned)eidx[N_EDGES + e];   // dst row
        if (d < N_NODES) atomicAdd(&cnt[d], 1);
    }
}

// ---------------- exclusive scan (3-phase) ----------------
__global__ void k_scan1(const int* __restrict__ cnt, int* __restrict__ rp,
                        int* __restrict__ bsum) {
    __shared__ int s[SCAN_T];
    int tid  = threadIdx.x;
    int base = blockIdx.x * SCAN_ELEMS + tid * SCAN_I;
    int v[SCAN_I];
    int loc = 0;
#pragma unroll
    for (int j = 0; j < SCAN_I; ++j) {
        int idx = base + j;
        v[j] = (idx < N_NODES) ? cnt[idx] : 0;
        loc += v[j];
    }
    s[tid] = loc;
    __syncthreads();
    for (int off = 1; off < SCAN_T; off <<= 1) {
        int t = (tid >= off) ? s[tid - off] : 0;
        __syncthreads();
        s[tid] += t;
        __syncthreads();
    }
    int run = s[tid] - loc;   // exclusive prefix for this thread
#pragma unroll
    for (int j = 0; j < SCAN_I; ++j) {
        int idx = base + j;
        if (idx < N_NODES) rp[idx] = run;
        run += v[j];
    }
    if (tid == SCAN_T - 1) bsum[blockIdx.x] = s[SCAN_T - 1];
}

__global__ void k_scan2(const int* __restrict__ bsum, int* __restrict__ boff,
                        int* __restrict__ rp) {
    int acc = 0;
    for (int i = 0; i < SCAN_NB; ++i) { boff[i] = acc; acc += bsum[i]; }
    rp[N_NODES] = acc;
}

__global__ void k_scan3(int* __restrict__ rp, const int* __restrict__ boff) {
    int off = boff[blockIdx.x];
#pragma unroll
    for (int j = 0; j < SCAN_I; ++j) {
        int i = blockIdx.x * SCAN_ELEMS + threadIdx.x + j * SCAN_T;
        if (i < N_NODES) rp[i] += off;
    }
}

// ---------------- dinv = rsqrt(deg) with self loop (+1) ----------------
__global__ void k_dinv(const int* __restrict__ cnt, float* __restrict__ dinv) {
    int i = blockIdx.x * blockDim.x + threadIdx.x;
    if (i < N_NODES) dinv[i] = rsqrtf(1.0f + (float)cnt[i]);
}

// ---------------- CSR fill (col = src, bucketed by dst) ----------------
__global__ void k_fill(const int* __restrict__ eidx, const int* __restrict__ rp,
                       int* __restrict__ cursor, int* __restrict__ col) {
    int e = blockIdx.x * blockDim.x + threadIdx.x;
    if (e < N_EDGES) {
        unsigned d = (unsigned)eidx[N_EDGES + e];
        unsigned s = (unsigned)eidx[e];
        if (d < N_NODES && s < N_NODES) {
            int pos = rp[d] + atomicAdd(&cursor[d], 1);
            col[pos] = (int)s;
        }
    }
}

// ---------------- GEMM: out = act(x @ W + b), all fp32 ----------------
// block = 256: tx = tid&31 (4 cols -> 128 cols), ty = tid>>5 (4 rows -> 32 rows/block)
#define KCH 64
template <bool RELU>
__global__ __launch_bounds__(256)
void k_gemm(const float* __restrict__ x, const float* __restrict__ W,
            const float* __restrict__ bias, float* __restrict__ out) {
    __shared__ __align__(16) float wlds[KCH][HDIM];     // 32 KB
    __shared__ __align__(16) float xs[32][KCH + 1];     // ~8.3 KB, +1 pad
    int tid  = threadIdx.x;
    int tx   = tid & 31, ty = tid >> 5;
    int row0 = blockIdx.x * 32;

    float4 bc = *(const float4*)&bias[tx * 4];

    float acc[4][4] = {};
    for (int kc = 0; kc < HDIM; kc += KCH) {
        // stage W chunk: 64x128 floats = 2048 float4, 8 per thread
#pragma unroll
        for (int i = 0; i < 8; ++i) {
            int id = tid + i * 256;            // float4 index in [0,2048)
            int kk = id >> 5, n4 = id & 31;
            *(float4*)&wlds[kk][n4 * 4] =
                *(const float4*)&W[(size_t)(kc + kk) * HDIM + n4 * 4];
        }
        // stage x chunk: 32 rows x 64 k = 512 float4, 2 per thread
#pragma unroll
        for (int i = 0; i < 2; ++i) {
            int id = tid + i * 256;            // float4 index in [0,512)
            int r = id >> 4, c4 = id & 15;
            float4 v = *(const float4*)&x[(size_t)(row0 + r) * HDIM + kc + c4 * 4];
            xs[r][c4 * 4 + 0] = v.x;
            xs[r][c4 * 4 + 1] = v.y;
            xs[r][c4 * 4 + 2] = v.z;
            xs[r][c4 * 4 + 3] = v.w;
        }
        __syncthreads();
#pragma unroll 8
        for (int kk = 0; kk < KCH; ++kk) {
            float4 b4 = *(const float4*)&wlds[kk][tx * 4];
            float a0 = xs[ty * 4 + 0][kk];
            float a1 = xs[ty * 4 + 1][kk];
            float a2 = xs[ty * 4 + 2][kk];
            float a3 = xs[ty * 4 + 3][kk];
            acc[0][0] += a0 * b4.x; acc[0][1] += a0 * b4.y; acc[0][2] += a0 * b4.z; acc[0][3] += a0 * b4.w;
            acc[1][0] += a1 * b4.x; acc[1][1] += a1 * b4.y; acc[1][2] += a1 * b4.z; acc[1][3] += a1 * b4.w;
            acc[2][0] += a2 * b4.x; acc[2][1] += a2 * b4.y; acc[2][2] += a2 * b4.z; acc[2][3] += a2 * b4.w;
            acc[3][0] += a3 * b4.x; acc[3][1] += a3 * b4.y; acc[3][2] += a3 * b4.z; acc[3][3] += a3 * b4.w;
        }
        __syncthreads();
    }
#pragma unroll
    for (int r = 0; r < 4; ++r) {
        int row = row0 + ty * 4 + r;
        float4 v;
        v.x = acc[r][0] + bc.x;
        v.y = acc[r][1] + bc.y;
        v.z = acc[r][2] + bc.z;
        v.w = acc[r][3] + bc.w;
        if (RELU) {
            v.x = fmaxf(v.x, 0.0f); v.y = fmaxf(v.y, 0.0f);
            v.z = fmaxf(v.z, 0.0f); v.w = fmaxf(v.w, 0.0f);
        }
        *(float4*)&out[(size_t)row * HDIM + tx * 4] = v;
    }
}

// ---- APPNP step: hout = 0.9 * dinv[i]*(sum_{s in N(i)} dinv[s] h[s] + dinv[i] h[i]) + 0.1 h0 ----
// one wave per node; lane handles 2 dims (float2)
__global__ __launch_bounds__(256)
void k_step(const float* __restrict__ hin, const float* __restrict__ h0,
            float* __restrict__ hout, const int* __restrict__ col,
            const int* __restrict__ rp, const float* __restrict__ dinv) {
    int gid  = blockIdx.x * blockDim.x + threadIdx.x;
    int node = gid >> 6;
    int lane = threadIdx.x & 63;
    if (node >= N_NODES) return;

    const float2* hin2 = (const float2*)hin;
    float di = dinv[node];
    float2 hi = hin2[(size_t)node * 64 + lane];
    float accx = di * hi.x, accy = di * hi.y;   // self-loop term (outer dinv applied later)

    int beg = rp[node], end = rp[node + 1];
    int e = beg;
    for (; e + 1 < end; e += 2) {
        int s0 = col[e], s1 = col[e + 1];
        float w0 = dinv[s0], w1 = dinv[s1];
        float2 a0 = hin2[(size_t)s0 * 64 + lane];
        float2 a1 = hin2[(size_t)s1 * 64 + lane];
        accx += w0 * a0.x + w1 * a1.x;
        accy += w0 * a0.y + w1 * a1.y;
    }
    if (e < end) {
        int s0 = col[e];
        float w0 = dinv[s0];
        float2 a0 = hin2[(size_t)s0 * 64 + lane];
        accx += w0 * a0.x;
        accy += w0 * a0.y;
    }
    float2 hv = ((const float2*)h0)[(size_t)node * 64 + lane];
    float2 o;
    o.x = 0.9f * di * accx + 0.1f * hv.x;
    o.y = 0.9f * di * accy + 0.1f * hv.y;
    ((float2*)hout)[(size_t)node * 64 + lane] = o;
}

extern "C" void kernel_launch(void* const* d_in, const int* in_sizes, int n_in,
                              void* d_out, int out_size, void* d_ws, size_t ws_size,
                              hipStream_t stream) {
    (void)in_sizes; (void)n_in; (void)out_size; (void)ws_size;
    const float* x  = (const float*)d_in[0];
    const int*   ei = (const int*)d_in[1];
    const float* W1 = (const float*)d_in[2];
    const float* b1 = (const float*)d_in[3];
    const float* W2 = (const float*)d_in[4];
    const float* b2 = (const float*)d_in[5];
    float* out = (float*)d_out;

    char* ws = (char*)d_ws;
    size_t off = 0;
    auto alloc = [&](size_t bytes) -> void* {
        void* p = ws + off;
        off += (bytes + 255) & ~(size_t)255;
        return p;
    };
    float* h0   = (float*)alloc(sizeof(float) * (size_t)N_NODES * HDIM);
    float* hA   = (float*)alloc(sizeof(float) * (size_t)N_NODES * HDIM);
    float* hB   = (float*)alloc(sizeof(float) * (size_t)N_NODES * HDIM);
    int*   col  = (int*)alloc(sizeof(int) * N_EDGES);
    int*   rp   = (int*)alloc(sizeof(int) * (N_NODES + 1));
    int*   cnt  = (int*)alloc(sizeof(int) * N_NODES);
    int*   cur  = (int*)alloc(sizeof(int) * N_NODES);
    float* dinv = (float*)alloc(sizeof(float) * N_NODES);
    int*   bsum = (int*)alloc(sizeof(int) * SCAN_NB);
    int*   boff = (int*)alloc(sizeof(int) * SCAN_NB);

    hipMemsetAsync(cnt, 0, sizeof(int) * N_NODES, stream);
    hipMemsetAsync(cur, 0, sizeof(int) * N_NODES, stream);

    k_count<<<N_EDGES / 256, 256, 0, stream>>>(ei, cnt);
    k_scan1<<<SCAN_NB, SCAN_T, 0, stream>>>(cnt, rp, bsum);
    k_scan2<<<1, 1, 0, stream>>>(bsum, boff, rp);
    k_scan3<<<SCAN_NB, SCAN_T, 0, stream>>>(rp, boff);
    k_dinv<<<(N_NODES + 255) / 256, 256, 0, stream>>>(cnt, dinv);
    k_fill<<<N_EDGES / 256, 256, 0, stream>>>(ei, rp, cur, col);

    k_gemm<true><<<N_NODES / 32, 256, 0, stream>>>(x, W1, b1, h0);

    const float* hin = h0;
    float* hout = hA;
    for (int k = 0; k < KSTEPS; ++k) {
        k_step<<<N_NODES / 4, 256, 0, stream>>>(hin, h0, hout, col, rp, dinv);
        hin = hout;
        hout = (hout == hA) ? hB : hA;
    }
    k_gemm<false><<<N_NODES / 32, 256, 0, stream>>>(hin, W2, b2, out);
}

// Round 3
// 1617.559 us; speedup vs baseline: 1.1524x; 1.1524x over previous
//
#include <hip/hip_runtime.h>
#include <stdint.h>

#define N_NODES 100000
#define N_EDGES 1600000
#define HDIM    128
#define KSTEPS  10

// ---- CSR-build scan config ----
#define SCAN_T     256
#define SCAN_I     4
#define SCAN_ELEMS (SCAN_T * SCAN_I)                         // 1024
#define SCAN_NB    ((N_NODES + SCAN_ELEMS - 1) / SCAN_ELEMS) // 98

// ---------------- degree count over dst (excluding self loop) ----------------
__global__ void k_count(const int* __restrict__ eidx, int* __restrict__ cnt) {
    int e = blockIdx.x * blockDim.x + threadIdx.x;
    if (e < N_EDGES) {
        unsigned d = (unsigned)eidx[N_EDGES + e];   // dst row
        if (d < N_NODES) atomicAdd(&cnt[d], 1);
    }
}

// ---------------- exclusive scan (3-phase) ----------------
__global__ void k_scan1(const int* __restrict__ cnt, int* __restrict__ rp,
                        int* __restrict__ bsum) {
    __shared__ int s[SCAN_T];
    int tid  = threadIdx.x;
    int base = blockIdx.x * SCAN_ELEMS + tid * SCAN_I;
    int v[SCAN_I];
    int loc = 0;
#pragma unroll
    for (int j = 0; j < SCAN_I; ++j) {
        int idx = base + j;
        v[j] = (idx < N_NODES) ? cnt[idx] : 0;
        loc += v[j];
    }
    s[tid] = loc;
    __syncthreads();
    for (int off = 1; off < SCAN_T; off <<= 1) {
        int t = (tid >= off) ? s[tid - off] : 0;
        __syncthreads();
        s[tid] += t;
        __syncthreads();
    }
    int run = s[tid] - loc;   // exclusive prefix for this thread
#pragma unroll
    for (int j = 0; j < SCAN_I; ++j) {
        int idx = base + j;
        if (idx < N_NODES) rp[idx] = run;
        run += v[j];
    }
    if (tid == SCAN_T - 1) bsum[blockIdx.x] = s[SCAN_T - 1];
}

__global__ void k_scan2(const int* __restrict__ bsum, int* __restrict__ boff,
                        int* __restrict__ rp) {
    int acc = 0;
    for (int i = 0; i < SCAN_NB; ++i) { boff[i] = acc; acc += bsum[i]; }
    rp[N_NODES] = acc;
}

__global__ void k_scan3(int* __restrict__ rp, const int* __restrict__ boff) {
    int off = boff[blockIdx.x];
#pragma unroll
    for (int j = 0; j < SCAN_I; ++j) {
        int i = blockIdx.x * SCAN_ELEMS + threadIdx.x + j * SCAN_T;
        if (i < N_NODES) rp[i] += off;
    }
}

// -------- dinv = rsqrt(1+deg), dsq = sqrt(1+deg) (self loop included) --------
__global__ void k_dinv(const int* __restrict__ cnt, float* __restrict__ dinv,
                       float* __restrict__ dsq) {
    int i = blockIdx.x * blockDim.x + threadIdx.x;
    if (i < N_NODES) {
        float d = 1.0f + (float)cnt[i];
        dinv[i] = rsqrtf(d);
        dsq[i]  = sqrtf(d);
    }
}

// ---------------- CSR fill (col = src, bucketed by dst) ----------------
__global__ void k_fill(const int* __restrict__ eidx, const int* __restrict__ rp,
                       int* __restrict__ cursor, int* __restrict__ col) {
    int e = blockIdx.x * blockDim.x + threadIdx.x;
    if (e < N_EDGES) {
        unsigned d = (unsigned)eidx[N_EDGES + e];
        unsigned s = (unsigned)eidx[e];
        if (d < N_NODES && s < N_NODES) {
            int pos = rp[d] + atomicAdd(&cursor[d], 1);
            col[pos] = (int)s;
        }
    }
}

// ---------------- GEMM1: u0 = dinv * relu(x @ W1 + b1), all fp32 ----------------
// block = 256: tx = tid&31 (4 cols -> 128 cols), ty = tid>>5 (4 rows -> 32 rows/block)
#define KCH 64
__global__ __launch_bounds__(256)
void k_gemm1(const float* __restrict__ x, const float* __restrict__ W,
             const float* __restrict__ bias, const float* __restrict__ dinv,
             float* __restrict__ out) {
    __shared__ __align__(16) float wlds[KCH][HDIM];     // 32 KB
    __shared__ __align__(16) float xs[32][KCH + 1];     // ~8.3 KB
    int tid  = threadIdx.x;
    int tx   = tid & 31, ty = tid >> 5;
    int row0 = blockIdx.x * 32;

    float4 bc = *(const float4*)&bias[tx * 4];

    float acc[4][4] = {};
    for (int kc = 0; kc < HDIM; kc += KCH) {
#pragma unroll
        for (int i = 0; i < 8; ++i) {
            int id = tid + i * 256;
            int kk = id >> 5, n4 = id & 31;
            *(float4*)&wlds[kk][n4 * 4] =
                *(const float4*)&W[(size_t)(kc + kk) * HDIM + n4 * 4];
        }
#pragma unroll
        for (int i = 0; i < 2; ++i) {
            int id = tid + i * 256;
            int r = id >> 4, c4 = id & 15;
            float4 v = *(const float4*)&x[(size_t)(row0 + r) * HDIM + kc + c4 * 4];
            xs[r][c4 * 4 + 0] = v.x;
            xs[r][c4 * 4 + 1] = v.y;
            xs[r][c4 * 4 + 2] = v.z;
            xs[r][c4 * 4 + 3] = v.w;
        }
        __syncthreads();
#pragma unroll 8
        for (int kk = 0; kk < KCH; ++kk) {
            float4 b4 = *(const float4*)&wlds[kk][tx * 4];
            float a0 = xs[ty * 4 + 0][kk];
            float a1 = xs[ty * 4 + 1][kk];
            float a2 = xs[ty * 4 + 2][kk];
            float a3 = xs[ty * 4 + 3][kk];
            acc[0][0] += a0 * b4.x; acc[0][1] += a0 * b4.y; acc[0][2] += a0 * b4.z; acc[0][3] += a0 * b4.w;
            acc[1][0] += a1 * b4.x; acc[1][1] += a1 * b4.y; acc[1][2] += a1 * b4.z; acc[1][3] += a1 * b4.w;
            acc[2][0] += a2 * b4.x; acc[2][1] += a2 * b4.y; acc[2][2] += a2 * b4.z; acc[2][3] += a2 * b4.w;
            acc[3][0] += a3 * b4.x; acc[3][1] += a3 * b4.y; acc[3][2] += a3 * b4.z; acc[3][3] += a3 * b4.w;
        }
        __syncthreads();
    }
#pragma unroll
    for (int r = 0; r < 4; ++r) {
        int row = row0 + ty * 4 + r;
        float di = dinv[row];
        float4 v;
        v.x = fmaxf(acc[r][0] + bc.x, 0.0f) * di;
        v.y = fmaxf(acc[r][1] + bc.y, 0.0f) * di;
        v.z = fmaxf(acc[r][2] + bc.z, 0.0f) * di;
        v.w = fmaxf(acc[r][3] + bc.w, 0.0f) * di;
        *(float4*)&out[(size_t)row * HDIM + tx * 4] = v;
    }
}

// ---------------- GEMM2: out = (dsq * u) @ W2 + b2, all fp32 ----------------
__global__ __launch_bounds__(256)
void k_gemm2(const float* __restrict__ u, const float* __restrict__ W,
             const float* __restrict__ bias, const float* __restrict__ dsq,
             float* __restrict__ out) {
    __shared__ __align__(16) float wlds[KCH][HDIM];
    __shared__ __align__(16) float xs[32][KCH + 1];
    int tid  = threadIdx.x;
    int tx   = tid & 31, ty = tid >> 5;
    int row0 = blockIdx.x * 32;

    float4 bc = *(const float4*)&bias[tx * 4];

    float acc[4][4] = {};
    for (int kc = 0; kc < HDIM; kc += KCH) {
#pragma unroll
        for (int i = 0; i < 8; ++i) {
            int id = tid + i * 256;
            int kk = id >> 5, n4 = id & 31;
            *(float4*)&wlds[kk][n4 * 4] =
                *(const float4*)&W[(size_t)(kc + kk) * HDIM + n4 * 4];
        }
#pragma unroll
        for (int i = 0; i < 2; ++i) {
            int id = tid + i * 256;
            int r = id >> 4, c4 = id & 15;
            float ds = dsq[row0 + r];
            float4 v = *(const float4*)&u[(size_t)(row0 + r) * HDIM + kc + c4 * 4];
            xs[r][c4 * 4 + 0] = v.x * ds;
            xs[r][c4 * 4 + 1] = v.y * ds;
            xs[r][c4 * 4 + 2] = v.z * ds;
            xs[r][c4 * 4 + 3] = v.w * ds;
        }
        __syncthreads();
#pragma unroll 8
        for (int kk = 0; kk < KCH; ++kk) {
            float4 b4 = *(const float4*)&wlds[kk][tx * 4];
            float a0 = xs[ty * 4 + 0][kk];
            float a1 = xs[ty * 4 + 1][kk];
            float a2 = xs[ty * 4 + 2][kk];
            float a3 = xs[ty * 4 + 3][kk];
            acc[0][0] += a0 * b4.x; acc[0][1] += a0 * b4.y; acc[0][2] += a0 * b4.z; acc[0][3] += a0 * b4.w;
            acc[1][0] += a1 * b4.x; acc[1][1] += a1 * b4.y; acc[1][2] += a1 * b4.z; acc[1][3] += a1 * b4.w;
            acc[2][0] += a2 * b4.x; acc[2][1] += a2 * b4.y; acc[2][2] += a2 * b4.z; acc[2][3] += a2 * b4.w;
            acc[3][0] += a3 * b4.x; acc[3][1] += a3 * b4.y; acc[3][2] += a3 * b4.z; acc[3][3] += a3 * b4.w;
        }
        __syncthreads();
    }
#pragma unroll
    for (int r = 0; r < 4; ++r) {
        int row = row0 + ty * 4 + r;
        float4 v;
        v.x = acc[r][0] + bc.x;
        v.y = acc[r][1] + bc.y;
        v.z = acc[r][2] + bc.z;
        v.w = acc[r][3] + bc.w;
        *(float4*)&out[(size_t)row * HDIM + tx * 4] = v;
    }
}

// ---- APPNP step in u-space: u' = 0.9*dinv[i]^2*(sum_{s in N(i)} u[s] + u[i]) + 0.1*u0 ----
// one wave per node; lane handles 2 dims (float2).
// node is forced to SGPR so rp/col index loads scalarize (s_load via K$),
// leaving vmcnt entirely for the 512B row gathers. 8-wide unroll for MLP.
__global__ __launch_bounds__(256)
void k_step(const float* __restrict__ uin, const float* __restrict__ u0,
            float* __restrict__ uout, const int* __restrict__ col,
            const int* __restrict__ rp, const float* __restrict__ dinv) {
    int wid  = (blockIdx.x * blockDim.x + threadIdx.x) >> 6;
    int node = __builtin_amdgcn_readfirstlane(wid);
    int lane = threadIdx.x & 63;
    if (node >= N_NODES) return;

    const float2* u2 = (const float2*)uin;
    size_t self = (size_t)node * 64 + lane;
    float2 us = u2[self];                      // issue early, overlaps index loads
    float2 uz = ((const float2*)u0)[self];
    float  di = dinv[node];
    float  w  = 0.9f * di * di;

    int beg = rp[node], end = rp[node + 1];
    float accx = us.x, accy = us.y;            // self-loop term

    int e = beg;
    for (; e + 8 <= end; e += 8) {
        int s0 = col[e + 0], s1 = col[e + 1], s2 = col[e + 2], s3 = col[e + 3];
        int s4 = col[e + 4], s5 = col[e + 5], s6 = col[e + 6], s7 = col[e + 7];
        float2 a0 = u2[(size_t)s0 * 64 + lane];
        float2 a1 = u2[(size_t)s1 * 64 + lane];
        float2 a2 = u2[(size_t)s2 * 64 + lane];
        float2 a3 = u2[(size_t)s3 * 64 + lane];
        float2 a4 = u2[(size_t)s4 * 64 + lane];
        float2 a5 = u2[(size_t)s5 * 64 + lane];
        float2 a6 = u2[(size_t)s6 * 64 + lane];
        float2 a7 = u2[(size_t)s7 * 64 + lane];
        accx += ((a0.x + a1.x) + (a2.x + a3.x)) + ((a4.x + a5.x) + (a6.x + a7.x));
        accy += ((a0.y + a1.y) + (a2.y + a3.y)) + ((a4.y + a5.y) + (a6.y + a7.y));
    }
    for (; e + 2 <= end; e += 2) {
        int s0 = col[e], s1 = col[e + 1];
        float2 a0 = u2[(size_t)s0 * 64 + lane];
        float2 a1 = u2[(size_t)s1 * 64 + lane];
        accx += a0.x + a1.x;
        accy += a0.y + a1.y;
    }
    if (e < end) {
        int s0 = col[e];
        float2 a0 = u2[(size_t)s0 * 64 + lane];
        accx += a0.x;
        accy += a0.y;
    }
    float2 o;
    o.x = w * accx + 0.1f * uz.x;
    o.y = w * accy + 0.1f * uz.y;
    ((float2*)uout)[self] = o;
}

extern "C" void kernel_launch(void* const* d_in, const int* in_sizes, int n_in,
                              void* d_out, int out_size, void* d_ws, size_t ws_size,
                              hipStream_t stream) {
    (void)in_sizes; (void)n_in; (void)out_size; (void)ws_size;
    const float* x  = (const float*)d_in[0];
    const int*   ei = (const int*)d_in[1];
    const float* W1 = (const float*)d_in[2];
    const float* b1 = (const float*)d_in[3];
    const float* W2 = (const float*)d_in[4];
    const float* b2 = (const float*)d_in[5];
    float* out = (float*)d_out;

    char* ws = (char*)d_ws;
    size_t off = 0;
    auto alloc = [&](size_t bytes) -> void* {
        void* p = ws + off;
        off += (bytes + 255) & ~(size_t)255;
        return p;
    };
    float* u0   = (float*)alloc(sizeof(float) * (size_t)N_NODES * HDIM);
    float* uA   = (float*)alloc(sizeof(float) * (size_t)N_NODES * HDIM);
    float* uB   = (float*)alloc(sizeof(float) * (size_t)N_NODES * HDIM);
    int*   col  = (int*)alloc(sizeof(int) * N_EDGES);
    int*   rp   = (int*)alloc(sizeof(int) * (N_NODES + 1));
    int*   cnt  = (int*)alloc(sizeof(int) * N_NODES);
    int*   cur  = (int*)alloc(sizeof(int) * N_NODES);
    float* dinv = (float*)alloc(sizeof(float) * N_NODES);
    float* dsq  = (float*)alloc(sizeof(float) * N_NODES);
    int*   bsum = (int*)alloc(sizeof(int) * SCAN_NB);
    int*   boff = (int*)alloc(sizeof(int) * SCAN_NB);

    hipMemsetAsync(cnt, 0, sizeof(int) * N_NODES, stream);
    hipMemsetAsync(cur, 0, sizeof(int) * N_NODES, stream);

    k_count<<<N_EDGES / 256, 256, 0, stream>>>(ei, cnt);
    k_scan1<<<SCAN_NB, SCAN_T, 0, stream>>>(cnt, rp, bsum);
    k_scan2<<<1, 1, 0, stream>>>(bsum, boff, rp);
    k_scan3<<<SCAN_NB, SCAN_T, 0, stream>>>(rp, boff);
    k_dinv<<<(N_NODES + 255) / 256, 256, 0, stream>>>(cnt, dinv, dsq);
    k_fill<<<N_EDGES / 256, 256, 0, stream>>>(ei, rp, cur, col);

    k_gemm1<<<N_NODES / 32, 256, 0, stream>>>(x, W1, b1, dinv, u0);

    const float* uin = u0;
    float* uout = uA;
    for (int k = 0; k < KSTEPS; ++k) {
        k_step<<<N_NODES / 4, 256, 0, stream>>>(uin, u0, uout, col, rp, dinv);
        uin = uout;
        uout = (uout == uA) ? uB : uA;
    }
    k_gemm2<<<N_NODES / 32, 256, 0, stream>>>(uin, W2, b2, dsq, out);
}

// Round 4
// 993.518 us; speedup vs baseline: 1.8762x; 1.6281x over previous
//
#include <hip/hip_runtime.h>
#include <stdint.h>

#define N_NODES 100000
#define N_EDGES 1600000
#define HDIM    128
#define KSTEPS  10

typedef unsigned int uint;

// ---- CSR-build scan config ----
#define SCAN_T     256
#define SCAN_I     4
#define SCAN_ELEMS (SCAN_T * SCAN_I)                         // 1024
#define SCAN_NB    ((N_NODES + SCAN_ELEMS - 1) / SCAN_ELEMS) // 98

// ---- bf16x2 helpers (RNE) ----
__device__ inline float2 bf2_to_f2(uint v) {
    float2 r;
    r.x = __uint_as_float(v << 16);
    r.y = __uint_as_float(v & 0xffff0000u);
    return r;
}
__device__ inline uint f_to_bf_bits(float f) {        // returns bf16 in low 16
    uint u = __float_as_uint(f);
    return (u + 0x7fffu + ((u >> 16) & 1u)) >> 16;
}
__device__ inline uint f2_to_bf2(float x, float y) {
    return f_to_bf_bits(x) | (f_to_bf_bits(y) << 16);
}

// ---------------- degree count over dst (excluding self loop) ----------------
__global__ void k_count(const int* __restrict__ eidx, int* __restrict__ cnt) {
    int e = blockIdx.x * blockDim.x + threadIdx.x;
    if (e < N_EDGES) {
        unsigned d = (unsigned)eidx[N_EDGES + e];   // dst row
        if (d < N_NODES) atomicAdd(&cnt[d], 1);
    }
}

// ---------------- exclusive scan (3-phase) ----------------
__global__ void k_scan1(const int* __restrict__ cnt, int* __restrict__ rp,
                        int* __restrict__ bsum) {
    __shared__ int s[SCAN_T];
    int tid  = threadIdx.x;
    int base = blockIdx.x * SCAN_ELEMS + tid * SCAN_I;
    int v[SCAN_I];
    int loc = 0;
#pragma unroll
    for (int j = 0; j < SCAN_I; ++j) {
        int idx = base + j;
        v[j] = (idx < N_NODES) ? cnt[idx] : 0;
        loc += v[j];
    }
    s[tid] = loc;
    __syncthreads();
    for (int off = 1; off < SCAN_T; off <<= 1) {
        int t = (tid >= off) ? s[tid - off] : 0;
        __syncthreads();
        s[tid] += t;
        __syncthreads();
    }
    int run = s[tid] - loc;   // exclusive prefix for this thread
#pragma unroll
    for (int j = 0; j < SCAN_I; ++j) {
        int idx = base + j;
        if (idx < N_NODES) rp[idx] = run;
        run += v[j];
    }
    if (tid == SCAN_T - 1) bsum[blockIdx.x] = s[SCAN_T - 1];
}

__global__ void k_scan2(const int* __restrict__ bsum, int* __restrict__ boff,
                        int* __restrict__ rp) {
    int acc = 0;
    for (int i = 0; i < SCAN_NB; ++i) { boff[i] = acc; acc += bsum[i]; }
    rp[N_NODES] = acc;
}

__global__ void k_scan3(int* __restrict__ rp, const int* __restrict__ boff) {
    int off = boff[blockIdx.x];
#pragma unroll
    for (int j = 0; j < SCAN_I; ++j) {
        int i = blockIdx.x * SCAN_ELEMS + threadIdx.x + j * SCAN_T;
        if (i < N_NODES) rp[i] += off;
    }
}

// -------- dinv = rsqrt(1+deg), dsq = sqrt(1+deg) (self loop included) --------
__global__ void k_dinv(const int* __restrict__ cnt, float* __restrict__ dinv,
                       float* __restrict__ dsq) {
    int i = blockIdx.x * blockDim.x + threadIdx.x;
    if (i < N_NODES) {
        float d = 1.0f + (float)cnt[i];
        dinv[i] = rsqrtf(d);
        dsq[i]  = sqrtf(d);
    }
}

// ---------------- CSR fill (col = src, bucketed by dst) ----------------
__global__ void k_fill(const int* __restrict__ eidx, const int* __restrict__ rp,
                       int* __restrict__ cursor, int* __restrict__ col) {
    int e = blockIdx.x * blockDim.x + threadIdx.x;
    if (e < N_EDGES) {
        unsigned d = (unsigned)eidx[N_EDGES + e];
        unsigned s = (unsigned)eidx[e];
        if (d < N_NODES && s < N_NODES) {
            int pos = rp[d] + atomicAdd(&cursor[d], 1);
            col[pos] = (int)s;
        }
    }
}

// ---------------- GEMM1: u0 = bf16( dinv * relu(x @ W1 + b1) ) ----------------
// block = 256: tx = tid&31 (4 cols -> 128 cols), ty = tid>>5 (4 rows -> 32 rows/block)
#define KCH 64
__global__ __launch_bounds__(256)
void k_gemm1(const float* __restrict__ x, const float* __restrict__ W,
             const float* __restrict__ bias, const float* __restrict__ dinv,
             uint* __restrict__ out) {
    __shared__ __align__(16) float wlds[KCH][HDIM];     // 32 KB
    __shared__ __align__(16) float xs[32][KCH + 1];     // ~8.3 KB
    int tid  = threadIdx.x;
    int tx   = tid & 31, ty = tid >> 5;
    int row0 = blockIdx.x * 32;

    float4 bc = *(const float4*)&bias[tx * 4];

    float acc[4][4] = {};
    for (int kc = 0; kc < HDIM; kc += KCH) {
#pragma unroll
        for (int i = 0; i < 8; ++i) {
            int id = tid + i * 256;
            int kk = id >> 5, n4 = id & 31;
            *(float4*)&wlds[kk][n4 * 4] =
                *(const float4*)&W[(size_t)(kc + kk) * HDIM + n4 * 4];
        }
#pragma unroll
        for (int i = 0; i < 2; ++i) {
            int id = tid + i * 256;
            int r = id >> 4, c4 = id & 15;
            float4 v = *(const float4*)&x[(size_t)(row0 + r) * HDIM + kc + c4 * 4];
            xs[r][c4 * 4 + 0] = v.x;
            xs[r][c4 * 4 + 1] = v.y;
            xs[r][c4 * 4 + 2] = v.z;
            xs[r][c4 * 4 + 3] = v.w;
        }
        __syncthreads();
#pragma unroll 8
        for (int kk = 0; kk < KCH; ++kk) {
            float4 b4 = *(const float4*)&wlds[kk][tx * 4];
            float a0 = xs[ty * 4 + 0][kk];
            float a1 = xs[ty * 4 + 1][kk];
            float a2 = xs[ty * 4 + 2][kk];
            float a3 = xs[ty * 4 + 3][kk];
            acc[0][0] += a0 * b4.x; acc[0][1] += a0 * b4.y; acc[0][2] += a0 * b4.z; acc[0][3] += a0 * b4.w;
            acc[1][0] += a1 * b4.x; acc[1][1] += a1 * b4.y; acc[1][2] += a1 * b4.z; acc[1][3] += a1 * b4.w;
            acc[2][0] += a2 * b4.x; acc[2][1] += a2 * b4.y; acc[2][2] += a2 * b4.z; acc[2][3] += a2 * b4.w;
            acc[3][0] += a3 * b4.x; acc[3][1] += a3 * b4.y; acc[3][2] += a3 * b4.z; acc[3][3] += a3 * b4.w;
        }
        __syncthreads();
    }
#pragma unroll
    for (int r = 0; r < 4; ++r) {
        int row = row0 + ty * 4 + r;
        float di = dinv[row];
        float v0 = fmaxf(acc[r][0] + bc.x, 0.0f) * di;
        float v1 = fmaxf(acc[r][1] + bc.y, 0.0f) * di;
        float v2 = fmaxf(acc[r][2] + bc.z, 0.0f) * di;
        float v3 = fmaxf(acc[r][3] + bc.w, 0.0f) * di;
        uint2 p;
        p.x = f2_to_bf2(v0, v1);
        p.y = f2_to_bf2(v2, v3);
        *(uint2*)&out[(size_t)row * 64 + tx * 2] = p;   // row = 64 uints (128 bf16)
    }
}

// ---------------- GEMM2: out = (dsq * bf16 u) @ W2 + b2, fp32 out ----------------
__global__ __launch_bounds__(256)
void k_gemm2(const uint* __restrict__ u, const float* __restrict__ W,
             const float* __restrict__ bias, const float* __restrict__ dsq,
             float* __restrict__ out) {
    __shared__ __align__(16) float wlds[KCH][HDIM];
    __shared__ __align__(16) float xs[32][KCH + 1];
    int tid  = threadIdx.x;
    int tx   = tid & 31, ty = tid >> 5;
    int row0 = blockIdx.x * 32;

    float4 bc = *(const float4*)&bias[tx * 4];

    float acc[4][4] = {};
    for (int kc = 0; kc < HDIM; kc += KCH) {
#pragma unroll
        for (int i = 0; i < 8; ++i) {
            int id = tid + i * 256;
            int kk = id >> 5, n4 = id & 31;
            *(float4*)&wlds[kk][n4 * 4] =
                *(const float4*)&W[(size_t)(kc + kk) * HDIM + n4 * 4];
        }
#pragma unroll
        for (int i = 0; i < 2; ++i) {
            int id = tid + i * 256;
            int r = id >> 4, c4 = id & 15;
            float ds = dsq[row0 + r];
            uint2 v = *(const uint2*)&u[(size_t)(row0 + r) * 64 + (kc >> 1) + c4 * 2];
            float2 f0 = bf2_to_f2(v.x);
            float2 f1 = bf2_to_f2(v.y);
            xs[r][c4 * 4 + 0] = f0.x * ds;
            xs[r][c4 * 4 + 1] = f0.y * ds;
            xs[r][c4 * 4 + 2] = f1.x * ds;
            xs[r][c4 * 4 + 3] = f1.y * ds;
        }
        __syncthreads();
#pragma unroll 8
        for (int kk = 0; kk < KCH; ++kk) {
            float4 b4 = *(const float4*)&wlds[kk][tx * 4];
            float a0 = xs[ty * 4 + 0][kk];
            float a1 = xs[ty * 4 + 1][kk];
            float a2 = xs[ty * 4 + 2][kk];
            float a3 = xs[ty * 4 + 3][kk];
            acc[0][0] += a0 * b4.x; acc[0][1] += a0 * b4.y; acc[0][2] += a0 * b4.z; acc[0][3] += a0 * b4.w;
            acc[1][0] += a1 * b4.x; acc[1][1] += a1 * b4.y; acc[1][2] += a1 * b4.z; acc[1][3] += a1 * b4.w;
            acc[2][0] += a2 * b4.x; acc[2][1] += a2 * b4.y; acc[2][2] += a2 * b4.z; acc[2][3] += a2 * b4.w;
            acc[3][0] += a3 * b4.x; acc[3][1] += a3 * b4.y; acc[3][2] += a3 * b4.z; acc[3][3] += a3 * b4.w;
        }
        __syncthreads();
    }
#pragma unroll
    for (int r = 0; r < 4; ++r) {
        int row = row0 + ty * 4 + r;
        float4 v;
        v.x = acc[r][0] + bc.x;
        v.y = acc[r][1] + bc.y;
        v.z = acc[r][2] + bc.z;
        v.w = acc[r][3] + bc.w;
        *(float4*)&out[(size_t)row * HDIM + tx * 4] = v;
    }
}

// ---- APPNP step, u stored bf16x2: u' = 0.9*dinv^2*(sum u[s] + u[i]) + 0.1*u0 ----
// one wave per node; lane handles 2 dims (one bf16x2 = 4B, row = 256B).
// fp32 accumulation in-register. u0 read + uout write nontemporal (one-touch streams).
__global__ __launch_bounds__(256)
void k_step(const uint* __restrict__ uin, const uint* __restrict__ u0,
            uint* __restrict__ uout, const int* __restrict__ col,
            const int* __restrict__ rp, const float* __restrict__ dinv) {
    int wid  = (blockIdx.x * blockDim.x + threadIdx.x) >> 6;
    int node = __builtin_amdgcn_readfirstlane(wid);
    int lane = threadIdx.x & 63;
    if (node >= N_NODES) return;

    size_t self = (size_t)node * 64 + lane;
    uint usv = uin[self];                              // self row (gather-hot region)
    uint uzv = __builtin_nontemporal_load(&u0[self]);  // one-touch stream
    float di = dinv[node];
    float w  = 0.9f * di * di;

    int beg = rp[node], end = rp[node + 1];
    float2 us = bf2_to_f2(usv);
    float accx = us.x, accy = us.y;                    // self-loop term

    int e = beg;
    for (; e + 8 <= end; e += 8) {
        int s0 = col[e + 0], s1 = col[e + 1], s2 = col[e + 2], s3 = col[e + 3];
        int s4 = col[e + 4], s5 = col[e + 5], s6 = col[e + 6], s7 = col[e + 7];
        uint b0 = uin[(size_t)s0 * 64 + lane];
        uint b1 = uin[(size_t)s1 * 64 + lane];
        uint b2 = uin[(size_t)s2 * 64 + lane];
        uint b3 = uin[(size_t)s3 * 64 + lane];
        uint b4 = uin[(size_t)s4 * 64 + lane];
        uint b5 = uin[(size_t)s5 * 64 + lane];
        uint b6 = uin[(size_t)s6 * 64 + lane];
        uint b7 = uin[(size_t)s7 * 64 + lane];
        float2 a0 = bf2_to_f2(b0), a1 = bf2_to_f2(b1);
        float2 a2 = bf2_to_f2(b2), a3 = bf2_to_f2(b3);
        float2 a4 = bf2_to_f2(b4), a5 = bf2_to_f2(b5);
        float2 a6 = bf2_to_f2(b6), a7 = bf2_to_f2(b7);
        accx += ((a0.x + a1.x) + (a2.x + a3.x)) + ((a4.x + a5.x) + (a6.x + a7.x));
        accy += ((a0.y + a1.y) + (a2.y + a3.y)) + ((a4.y + a5.y) + (a6.y + a7.y));
    }
    for (; e + 2 <= end; e += 2) {
        int s0 = col[e], s1 = col[e + 1];
        uint b0 = uin[(size_t)s0 * 64 + lane];
        uint b1 = uin[(size_t)s1 * 64 + lane];
        float2 a0 = bf2_to_f2(b0), a1 = bf2_to_f2(b1);
        accx += a0.x + a1.x;
        accy += a0.y + a1.y;
    }
    if (e < end) {
        uint b0 = uin[(size_t)col[e] * 64 + lane];
        float2 a0 = bf2_to_f2(b0);
        accx += a0.x;
        accy += a0.y;
    }
    float2 uz = bf2_to_f2(uzv);
    float ox = w * accx + 0.1f * uz.x;
    float oy = w * accy + 0.1f * uz.y;
    __builtin_nontemporal_store(f2_to_bf2(ox, oy), &uout[self]);
}

extern "C" void kernel_launch(void* const* d_in, const int* in_sizes, int n_in,
                              void* d_out, int out_size, void* d_ws, size_t ws_size,
                              hipStream_t stream) {
    (void)in_sizes; (void)n_in; (void)out_size; (void)ws_size;
    const float* x  = (const float*)d_in[0];
    const int*   ei = (const int*)d_in[1];
    const float* W1 = (const float*)d_in[2];
    const float* b1 = (const float*)d_in[3];
    const float* W2 = (const float*)d_in[4];
    const float* b2 = (const float*)d_in[5];
    float* out = (float*)d_out;

    char* ws = (char*)d_ws;
    size_t off = 0;
    auto alloc = [&](size_t bytes) -> void* {
        void* p = ws + off;
        off += (bytes + 255) & ~(size_t)255;
        return p;
    };
    uint*  u0   = (uint*)alloc(sizeof(uint) * (size_t)N_NODES * 64);   // bf16x2 rows
    uint*  uA   = (uint*)alloc(sizeof(uint) * (size_t)N_NODES * 64);
    uint*  uB   = (uint*)alloc(sizeof(uint) * (size_t)N_NODES * 64);
    int*   col  = (int*)alloc(sizeof(int) * N_EDGES);
    int*   rp   = (int*)alloc(sizeof(int) * (N_NODES + 1));
    int*   cnt  = (int*)alloc(sizeof(int) * N_NODES);
    int*   cur  = (int*)alloc(sizeof(int) * N_NODES);
    float* dinv = (float*)alloc(sizeof(float) * N_NODES);
    float* dsq  = (float*)alloc(sizeof(float) * N_NODES);
    int*   bsum = (int*)alloc(sizeof(int) * SCAN_NB);
    int*   boff = (int*)alloc(sizeof(int) * SCAN_NB);

    hipMemsetAsync(cnt, 0, sizeof(int) * N_NODES, stream);
    hipMemsetAsync(cur, 0, sizeof(int) * N_NODES, stream);

    k_count<<<N_EDGES / 256, 256, 0, stream>>>(ei, cnt);
    k_scan1<<<SCAN_NB, SCAN_T, 0, stream>>>(cnt, rp, bsum);
    k_scan2<<<1, 1, 0, stream>>>(bsum, boff, rp);
    k_scan3<<<SCAN_NB, SCAN_T, 0, stream>>>(rp, boff);
    k_dinv<<<(N_NODES + 255) / 256, 256, 0, stream>>>(cnt, dinv, dsq);
    k_fill<<<N_EDGES / 256, 256, 0, stream>>>(ei, rp, cur, col);

    k_gemm1<<<N_NODES / 32, 256, 0, stream>>>(x, W1, b1, dinv, u0);

    const uint* uin = u0;
    uint* uout = uA;
    for (int k = 0; k < KSTEPS; ++k) {
        k_step<<<N_NODES / 4, 256, 0, stream>>>(uin, u0, uout, col, rp, dinv);
        uin = uout;
        uout = (uout == uA) ? uB : uA;
    }
    k_gemm2<<<N_NODES / 32, 256, 0, stream>>>(uin, W2, b2, dsq, out);
}

// Round 5
// 924.862 us; speedup vs baseline: 2.0155x; 1.0742x over previous
//
#include <hip/hip_runtime.h>
#include <stdint.h>

#define N_NODES 100000
#define N_EDGES 1600000
#define HDIM    128
#define KSTEPS  10
#define NZONE   8
#define ZDIV    12500u            // N_NODES / NZONE

typedef unsigned int uint;

// ---- CSR-build scan config ----
#define SCAN_T     256
#define SCAN_I     4
#define SCAN_ELEMS (SCAN_T * SCAN_I)                         // 1024
#define SCAN_NB    ((N_NODES + SCAN_ELEMS - 1) / SCAN_ELEMS) // 98

// ---- bf16x2 helpers (RNE) ----
__device__ inline float2 bf2_to_f2(uint v) {
    float2 r;
    r.x = __uint_as_float(v << 16);
    r.y = __uint_as_float(v & 0xffff0000u);
    return r;
}
__device__ inline uint f_to_bf_bits(float f) {        // returns bf16 in low 16
    uint u = __float_as_uint(f);
    return (u + 0x7fffu + ((u >> 16) & 1u)) >> 16;
}
__device__ inline uint f2_to_bf2(float x, float y) {
    return f_to_bf_bits(x) | (f_to_bf_bits(y) << 16);
}

// ------- fused degree-count + in-bucket position (one atomic pass) -------
__global__ void k_countpos(const int* __restrict__ eidx, int* __restrict__ cnt,
                           int* __restrict__ pos) {
    int e0 = (blockIdx.x * blockDim.x + threadIdx.x) * 4;
    if (e0 < N_EDGES) {
        int4 d4 = *(const int4*)&eidx[N_EDGES + e0];
        int4 p;
        p.x = atomicAdd(&cnt[d4.x], 1);
        p.y = atomicAdd(&cnt[d4.y], 1);
        p.z = atomicAdd(&cnt[d4.z], 1);
        p.w = atomicAdd(&cnt[d4.w], 1);
        *(int4*)&pos[e0] = p;
    }
}

// ---------------- exclusive scan (3-phase) ----------------
__global__ void k_scan1(const int* __restrict__ cnt, int* __restrict__ rp,
                        int* __restrict__ bsum) {
    __shared__ int s[SCAN_T];
    int tid  = threadIdx.x;
    int base = blockIdx.x * SCAN_ELEMS + tid * SCAN_I;
    int v[SCAN_I];
    int loc = 0;
#pragma unroll
    for (int j = 0; j < SCAN_I; ++j) {
        int idx = base + j;
        v[j] = (idx < N_NODES) ? cnt[idx] : 0;
        loc += v[j];
    }
    s[tid] = loc;
    __syncthreads();
    for (int off = 1; off < SCAN_T; off <<= 1) {
        int t = (tid >= off) ? s[tid - off] : 0;
        __syncthreads();
        s[tid] += t;
        __syncthreads();
    }
    int run = s[tid] - loc;   // exclusive prefix for this thread
#pragma unroll
    for (int j = 0; j < SCAN_I; ++j) {
        int idx = base + j;
        if (idx < N_NODES) rp[idx] = run;
        run += v[j];
    }
    if (tid == SCAN_T - 1) bsum[blockIdx.x] = s[SCAN_T - 1];
}

__global__ void k_scan2(const int* __restrict__ bsum, int* __restrict__ boff,
                        int* __restrict__ rp) {
    int acc = 0;
    for (int i = 0; i < SCAN_NB; ++i) { boff[i] = acc; acc += bsum[i]; }
    rp[N_NODES] = acc;
}

__global__ void k_scan3(int* __restrict__ rp, const int* __restrict__ boff) {
    int off = boff[blockIdx.x];
#pragma unroll
    for (int j = 0; j < SCAN_I; ++j) {
        int i = blockIdx.x * SCAN_ELEMS + threadIdx.x + j * SCAN_T;
        if (i < N_NODES) rp[i] += off;
    }
}

// -------- dinv = rsqrt(1+deg), dsq = sqrt(1+deg) (self loop included) --------
__global__ void k_dinv(const int* __restrict__ cnt, float* __restrict__ dinv,
                       float* __restrict__ dsq) {
    int i = blockIdx.x * blockDim.x + threadIdx.x;
    if (i < N_NODES) {
        float d = 1.0f + (float)cnt[i];
        dinv[i] = rsqrtf(d);
        dsq[i]  = sqrtf(d);
    }
}

// ------- zone-partitioned CSR fill, atomic-free -------
// grid = (NZONE, FECH); linear block id = z + NZONE*c -> blocks of one zone land
// on one XCD (round-robin heuristic) -> col lines for a zone dirty one L2 only.
#define FCHUNK 8192
#define FECH   ((N_EDGES + FCHUNK - 1) / FCHUNK)
__global__ __launch_bounds__(256)
void k_fill2(const int* __restrict__ eidx, const int* __restrict__ rp,
             const int* __restrict__ pos, int* __restrict__ col) {
    uint zone = blockIdx.x;
    int  base = blockIdx.y * FCHUNK;
#pragma unroll
    for (int i = 0; i < FCHUNK / 1024; ++i) {     // 8 iters x 1024 edges/block
        int e0 = base + (i * 256 + (int)threadIdx.x) * 4;
        if (e0 < N_EDGES) {
            int4 d4 = *(const int4*)&eidx[N_EDGES + e0];
            int4 s4 = *(const int4*)&eidx[e0];
            int4 p4 = *(const int4*)&pos[e0];
            if ((uint)d4.x / ZDIV == zone) col[rp[d4.x] + p4.x] = s4.x;
            if ((uint)d4.y / ZDIV == zone) col[rp[d4.y] + p4.y] = s4.y;
            if ((uint)d4.z / ZDIV == zone) col[rp[d4.z] + p4.z] = s4.z;
            if ((uint)d4.w / ZDIV == zone) col[rp[d4.w] + p4.w] = s4.w;
        }
    }
}

// ---------------- GEMM1: u0 = bf16( dinv * relu(x @ W1 + b1) ) ----------------
#define KCH 64
__global__ __launch_bounds__(256)
void k_gemm1(const float* __restrict__ x, const float* __restrict__ W,
             const float* __restrict__ bias, const float* __restrict__ dinv,
             uint* __restrict__ out) {
    __shared__ __align__(16) float wlds[KCH][HDIM];     // 32 KB
    __shared__ __align__(16) float xs[32][KCH + 1];     // ~8.3 KB
    int tid  = threadIdx.x;
    int tx   = tid & 31, ty = tid >> 5;
    int row0 = blockIdx.x * 32;

    float4 bc = *(const float4*)&bias[tx * 4];

    float acc[4][4] = {};
    for (int kc = 0; kc < HDIM; kc += KCH) {
#pragma unroll
        for (int i = 0; i < 8; ++i) {
            int id = tid + i * 256;
            int kk = id >> 5, n4 = id & 31;
            *(float4*)&wlds[kk][n4 * 4] =
                *(const float4*)&W[(size_t)(kc + kk) * HDIM + n4 * 4];
        }
#pragma unroll
        for (int i = 0; i < 2; ++i) {
            int id = tid + i * 256;
            int r = id >> 4, c4 = id & 15;
            float4 v = *(const float4*)&x[(size_t)(row0 + r) * HDIM + kc + c4 * 4];
            xs[r][c4 * 4 + 0] = v.x;
            xs[r][c4 * 4 + 1] = v.y;
            xs[r][c4 * 4 + 2] = v.z;
            xs[r][c4 * 4 + 3] = v.w;
        }
        __syncthreads();
#pragma unroll 8
        for (int kk = 0; kk < KCH; ++kk) {
            float4 b4 = *(const float4*)&wlds[kk][tx * 4];
            float a0 = xs[ty * 4 + 0][kk];
            float a1 = xs[ty * 4 + 1][kk];
            float a2 = xs[ty * 4 + 2][kk];
            float a3 = xs[ty * 4 + 3][kk];
            acc[0][0] += a0 * b4.x; acc[0][1] += a0 * b4.y; acc[0][2] += a0 * b4.z; acc[0][3] += a0 * b4.w;
            acc[1][0] += a1 * b4.x; acc[1][1] += a1 * b4.y; acc[1][2] += a1 * b4.z; acc[1][3] += a1 * b4.w;
            acc[2][0] += a2 * b4.x; acc[2][1] += a2 * b4.y; acc[2][2] += a2 * b4.z; acc[2][3] += a2 * b4.w;
            acc[3][0] += a3 * b4.x; acc[3][1] += a3 * b4.y; acc[3][2] += a3 * b4.z; acc[3][3] += a3 * b4.w;
        }
        __syncthreads();
    }
#pragma unroll
    for (int r = 0; r < 4; ++r) {
        int row = row0 + ty * 4 + r;
        float di = dinv[row];
        float v0 = fmaxf(acc[r][0] + bc.x, 0.0f) * di;
        float v1 = fmaxf(acc[r][1] + bc.y, 0.0f) * di;
        float v2 = fmaxf(acc[r][2] + bc.z, 0.0f) * di;
        float v3 = fmaxf(acc[r][3] + bc.w, 0.0f) * di;
        uint2 p;
        p.x = f2_to_bf2(v0, v1);
        p.y = f2_to_bf2(v2, v3);
        *(uint2*)&out[(size_t)row * 64 + tx * 2] = p;   // row = 64 uints (128 bf16)
    }
}

// ---------------- GEMM2: out = (dsq * bf16 u) @ W2 + b2, fp32 out ----------------
__global__ __launch_bounds__(256)
void k_gemm2(const uint* __restrict__ u, const float* __restrict__ W,
             const float* __restrict__ bias, const float* __restrict__ dsq,
             float* __restrict__ out) {
    __shared__ __align__(16) float wlds[KCH][HDIM];
    __shared__ __align__(16) float xs[32][KCH + 1];
    int tid  = threadIdx.x;
    int tx   = tid & 31, ty = tid >> 5;
    int row0 = blockIdx.x * 32;

    float4 bc = *(const float4*)&bias[tx * 4];

    float acc[4][4] = {};
    for (int kc = 0; kc < HDIM; kc += KCH) {
#pragma unroll
        for (int i = 0; i < 8; ++i) {
            int id = tid + i * 256;
            int kk = id >> 5, n4 = id & 31;
            *(float4*)&wlds[kk][n4 * 4] =
                *(const float4*)&W[(size_t)(kc + kk) * HDIM + n4 * 4];
        }
#pragma unroll
        for (int i = 0; i < 2; ++i) {
            int id = tid + i * 256;
            int r = id >> 4, c4 = id & 15;
            float ds = dsq[row0 + r];
            uint2 v = *(const uint2*)&u[(size_t)(row0 + r) * 64 + (kc >> 1) + c4 * 2];
            float2 f0 = bf2_to_f2(v.x);
            float2 f1 = bf2_to_f2(v.y);
            xs[r][c4 * 4 + 0] = f0.x * ds;
            xs[r][c4 * 4 + 1] = f0.y * ds;
            xs[r][c4 * 4 + 2] = f1.x * ds;
            xs[r][c4 * 4 + 3] = f1.y * ds;
        }
        __syncthreads();
#pragma unroll 8
        for (int kk = 0; kk < KCH; ++kk) {
            float4 b4 = *(const float4*)&wlds[kk][tx * 4];
            float a0 = xs[ty * 4 + 0][kk];
            float a1 = xs[ty * 4 + 1][kk];
            float a2 = xs[ty * 4 + 2][kk];
            float a3 = xs[ty * 4 + 3][kk];
            acc[0][0] += a0 * b4.x; acc[0][1] += a0 * b4.y; acc[0][2] += a0 * b4.z; acc[0][3] += a0 * b4.w;
            acc[1][0] += a1 * b4.x; acc[1][1] += a1 * b4.y; acc[1][2] += a1 * b4.z; acc[1][3] += a1 * b4.w;
            acc[2][0] += a2 * b4.x; acc[2][1] += a2 * b4.y; acc[2][2] += a2 * b4.z; acc[2][3] += a2 * b4.w;
            acc[3][0] += a3 * b4.x; acc[3][1] += a3 * b4.y; acc[3][2] += a3 * b4.z; acc[3][3] += a3 * b4.w;
        }
        __syncthreads();
    }
#pragma unroll
    for (int r = 0; r < 4; ++r) {
        int row = row0 + ty * 4 + r;
        float4 v;
        v.x = acc[r][0] + bc.x;
        v.y = acc[r][1] + bc.y;
        v.z = acc[r][2] + bc.z;
        v.w = acc[r][3] + bc.w;
        *(float4*)&out[(size_t)row * HDIM + tx * 4] = v;
    }
}

// ---- APPNP step, u stored bf16x2: u' = 0.9*dinv^2*(sum u[s] + u[i]) + 0.1*u0 ----
__global__ __launch_bounds__(256)
void k_step(const uint* __restrict__ uin, const uint* __restrict__ u0,
            uint* __restrict__ uout, const int* __restrict__ col,
            const int* __restrict__ rp, const float* __restrict__ dinv) {
    int wid  = (blockIdx.x * blockDim.x + threadIdx.x) >> 6;
    int node = __builtin_amdgcn_readfirstlane(wid);
    int lane = threadIdx.x & 63;
    if (node >= N_NODES) return;

    size_t self = (size_t)node * 64 + lane;
    uint usv = uin[self];                              // self row (gather-hot region)
    uint uzv = __builtin_nontemporal_load(&u0[self]);  // one-touch stream
    float di = dinv[node];
    float w  = 0.9f * di * di;

    int beg = rp[node], end = rp[node + 1];
    float2 us = bf2_to_f2(usv);
    float accx = us.x, accy = us.y;                    // self-loop term

    int e = beg;
    for (; e + 8 <= end; e += 8) {
        int s0 = col[e + 0], s1 = col[e + 1], s2 = col[e + 2], s3 = col[e + 3];
        int s4 = col[e + 4], s5 = col[e + 5], s6 = col[e + 6], s7 = col[e + 7];
        uint b0 = uin[(size_t)s0 * 64 + lane];
        uint b1 = uin[(size_t)s1 * 64 + lane];
        uint b2 = uin[(size_t)s2 * 64 + lane];
        uint b3 = uin[(size_t)s3 * 64 + lane];
        uint b4 = uin[(size_t)s4 * 64 + lane];
        uint b5 = uin[(size_t)s5 * 64 + lane];
        uint b6 = uin[(size_t)s6 * 64 + lane];
        uint b7 = uin[(size_t)s7 * 64 + lane];
        float2 a0 = bf2_to_f2(b0), a1 = bf2_to_f2(b1);
        float2 a2 = bf2_to_f2(b2), a3 = bf2_to_f2(b3);
        float2 a4 = bf2_to_f2(b4), a5 = bf2_to_f2(b5);
        float2 a6 = bf2_to_f2(b6), a7 = bf2_to_f2(b7);
        accx += ((a0.x + a1.x) + (a2.x + a3.x)) + ((a4.x + a5.x) + (a6.x + a7.x));
        accy += ((a0.y + a1.y) + (a2.y + a3.y)) + ((a4.y + a5.y) + (a6.y + a7.y));
    }
    if (e + 4 <= end) {
        int s0 = col[e], s1 = col[e + 1], s2 = col[e + 2], s3 = col[e + 3];
        uint b0 = uin[(size_t)s0 * 64 + lane];
        uint b1 = uin[(size_t)s1 * 64 + lane];
        uint b2 = uin[(size_t)s2 * 64 + lane];
        uint b3 = uin[(size_t)s3 * 64 + lane];
        float2 a0 = bf2_to_f2(b0), a1 = bf2_to_f2(b1);
        float2 a2 = bf2_to_f2(b2), a3 = bf2_to_f2(b3);
        accx += (a0.x + a1.x) + (a2.x + a3.x);
        accy += (a0.y + a1.y) + (a2.y + a3.y);
        e += 4;
    }
    if (e + 2 <= end) {
        int s0 = col[e], s1 = col[e + 1];
        uint b0 = uin[(size_t)s0 * 64 + lane];
        uint b1 = uin[(size_t)s1 * 64 + lane];
        float2 a0 = bf2_to_f2(b0), a1 = bf2_to_f2(b1);
        accx += a0.x + a1.x;
        accy += a0.y + a1.y;
        e += 2;
    }
    if (e < end) {
        uint b0 = uin[(size_t)col[e] * 64 + lane];
        float2 a0 = bf2_to_f2(b0);
        accx += a0.x;
        accy += a0.y;
    }
    float2 uz = bf2_to_f2(uzv);
    float ox = w * accx + 0.1f * uz.x;
    float oy = w * accy + 0.1f * uz.y;
    __builtin_nontemporal_store(f2_to_bf2(ox, oy), &uout[self]);
}

extern "C" void kernel_launch(void* const* d_in, const int* in_sizes, int n_in,
                              void* d_out, int out_size, void* d_ws, size_t ws_size,
                              hipStream_t stream) {
    (void)in_sizes; (void)n_in; (void)out_size; (void)ws_size;
    const float* x  = (const float*)d_in[0];
    const int*   ei = (const int*)d_in[1];
    const float* W1 = (const float*)d_in[2];
    const float* b1 = (const float*)d_in[3];
    const float* W2 = (const float*)d_in[4];
    const float* b2 = (const float*)d_in[5];
    float* out = (float*)d_out;

    char* ws = (char*)d_ws;
    size_t off = 0;
    auto alloc = [&](size_t bytes) -> void* {
        void* p = ws + off;
        off += (bytes + 255) & ~(size_t)255;
        return p;
    };
    uint*  u0   = (uint*)alloc(sizeof(uint) * (size_t)N_NODES * 64);   // bf16x2 rows
    uint*  uA   = (uint*)alloc(sizeof(uint) * (size_t)N_NODES * 64);
    uint*  uB   = (uint*)alloc(sizeof(uint) * (size_t)N_NODES * 64);
    int*   col  = (int*)alloc(sizeof(int) * N_EDGES);
    int*   pos  = (int*)alloc(sizeof(int) * N_EDGES);
    int*   rp   = (int*)alloc(sizeof(int) * (N_NODES + 1));
    int*   cnt  = (int*)alloc(sizeof(int) * N_NODES);
    float* dinv = (float*)alloc(sizeof(float) * N_NODES);
    float* dsq  = (float*)alloc(sizeof(float) * N_NODES);
    int*   bsum = (int*)alloc(sizeof(int) * SCAN_NB);
    int*   boff = (int*)alloc(sizeof(int) * SCAN_NB);

    hipMemsetAsync(cnt, 0, sizeof(int) * N_NODES, stream);

    k_countpos<<<(N_EDGES / 4 + 255) / 256, 256, 0, stream>>>(ei, cnt, pos);
    k_scan1<<<SCAN_NB, SCAN_T, 0, stream>>>(cnt, rp, bsum);
    k_scan2<<<1, 1, 0, stream>>>(bsum, boff, rp);
    k_scan3<<<SCAN_NB, SCAN_T, 0, stream>>>(rp, boff);
    k_dinv<<<(N_NODES + 255) / 256, 256, 0, stream>>>(cnt, dinv, dsq);
    {
        dim3 g(NZONE, FECH);
        k_fill2<<<g, 256, 0, stream>>>(ei, rp, pos, col);
    }

    k_gemm1<<<N_NODES / 32, 256, 0, stream>>>(x, W1, b1, dinv, u0);

    const uint* uin = u0;
    uint* uout = uA;
    for (int k = 0; k < KSTEPS; ++k) {
        k_step<<<N_NODES / 4, 256, 0, stream>>>(uin, u0, uout, col, rp, dinv);
        uin = uout;
        uout = (uout == uA) ? uB : uA;
    }
    k_gemm2<<<N_NODES / 32, 256, 0, stream>>>(uin, W2, b2, dsq, out);
}